// Round 1
// baseline (199.611 us; speedup 1.0000x reference)
//
#include <hip/hip_runtime.h>

// VSGNet fused pipeline — fp32 in/out, bf16 MFMA compute.
// B=64 P=16 L=16 D=1024 SP=32 PROJ=512 ACT=29, C=16384.
// R9 post-mortem: fused_gemms 50us, MfmaUtil 4.6%, VALUBusy 3.3%, HBM 7.5%,
// Occupancy 29.5% -> pure latency-bound; FETCH 21MB (vs ~9MB unique) = panel
// re-reads served by L3 (different XCDs), ~400-600cyc latency vs 156cyc
// depth-2 budget.
// R10: (1) depth-4 k-step pipeline (16 loads in flight/wave) in all K=1024
// loops + mega's K=512 loops; (2) XCD-bijective block swizzle (888=8*111,
// 512=8*64) so n-tiles sharing an A-panel hit the same XCD's L2; (3) memset
// folded into prep_all, converts upgraded to float4.

typedef unsigned short u16;   // bf16 bits
typedef short s16x8 __attribute__((ext_vector_type(8)));
typedef float f32x4 __attribute__((ext_vector_type(4)));

__device__ __forceinline__ u16 f2b(float f) {
    union { float f; unsigned int i; } v; v.f = f;
    unsigned int r = (v.i + 0x7fffu + ((v.i >> 16) & 1u)) >> 16;  // RNE
    return (u16)r;
}
__device__ __forceinline__ float b2f(u16 u) {
    union { float f; unsigned int i; } v; v.i = ((unsigned int)u) << 16; return v.f;
}
__device__ __forceinline__ unsigned int pack2(float x, float y) {
    return (unsigned int)f2b(x) | ((unsigned int)f2b(y) << 16);
}

// ---------------- workspace layout (bytes) ----------------
#define OFF_WSPATT 0u         // [512][32]  bf16
#define OFF_WREFT  32768u     // [32][512]  bf16 (rows 29..31 zero)
#define OFF_WATTT  65536u     // [32][512]  bf16
#define OFF_WGT    98304u     // [32][2048] bf16
#define OFF_PP     229376u    // [1024][512] bf16
#define OFF_PO     1277952u   // [1024][512] bf16
#define OFF_PC     2326528u   // [64][512]  bf16
#define OFF_ADJ    2392064u   // [16384] f32
#define OFF_HP     2457600u   // [1024][32] f32
#define OFF_HOF    2588672u   // [1024][32] f32
#define OFF_YH     2719744u   // [1024][32] f32
#define OFF_ZO     2850816u   // [960][32]  f32
#define ZERO_OFF   2457600u
#define ZERO_LEN   516096u
#define OFF_WVIST2 2973696u   // [512][3072] bf16 (n-major, k contiguous)
#define OFF_WHOT2  6119424u   // [1024][1024] bf16
#define OFF_WOHT2  8216576u   // [1024][1024] bf16
#define OFF_PEOB   10313728u  // [1024][1024] bf16
#define OFF_OBJB   12410880u  // [1024][1024] bf16
#define OFF_CTXB   14508032u  // [64][1024]  bf16
#define OFF_SPATB  14639104u  // [16384][32] bf16

// ---------------- prep: LDS-tiled big transposes + vectorized converts ------
// bids [0,896): 64x64 transpose tiles (Who:256, Woh:256, Wvis:384)
// bids [896,1408): grid-stride converts + small head transposes + ws zeroing
__global__ __launch_bounds__(256) void prep_all(
    const float* __restrict__ people, const float* __restrict__ objects,
    const float* __restrict__ context, const float* __restrict__ spatial,
    const float* __restrict__ Wvis, const float* __restrict__ Who,
    const float* __restrict__ Woh, const float* __restrict__ Wspat,
    const float* __restrict__ Wref, const float* __restrict__ Watt,
    const float* __restrict__ Wg,
    u16* __restrict__ peoB, u16* __restrict__ objB, u16* __restrict__ ctxB,
    u16* __restrict__ spatB, u16* __restrict__ WvisT, u16* __restrict__ WhoT,
    u16* __restrict__ WohT, u16* __restrict__ WspatT, u16* __restrict__ WrefT,
    u16* __restrict__ WattT, u16* __restrict__ WgT, float* __restrict__ zeroWS)
{
    __shared__ float S[64][65];
    int bid = blockIdx.x, t = threadIdx.x;
    if (bid < 896) {
        const float* src; u16* dst; int N, K, kt, nt;
        int tb = bid;
        if (tb < 256)      { src = Who;  dst = WhoT;  K = 1024; N = 1024; kt = tb >> 4; nt = tb & 15; }
        else if (tb < 512) { tb -= 256; src = Woh;  dst = WohT;  K = 1024; N = 1024; kt = tb >> 4; nt = tb & 15; }
        else               { tb -= 512; src = Wvis; dst = WvisT; K = 3072; N = 512;  kt = tb >> 3; nt = tb & 7; }
        int k0 = kt * 64, n0 = nt * 64;
        int tx = t & 63, ty = t >> 6;   // 4 rows/pass
#pragma unroll
        for (int i = 0; i < 16; i++)
            S[ty + 4 * i][tx] = src[(size_t)(k0 + ty + 4 * i) * N + n0 + tx];
        __syncthreads();
#pragma unroll
        for (int i = 0; i < 16; i++)
            dst[(size_t)(n0 + ty + 4 * i) * K + k0 + tx] = f2b(S[tx][ty + 4 * i]);
        return;
    }
    int g = (bid - 896) * 256 + t;
    const int gsz = 512 * 256;
    for (int i = g; i < 262144; i += gsz) {   // people (1M floats as float4)
        float4 v = ((const float4*)people)[i];
        ((uint2*)peoB)[i] = make_uint2(pack2(v.x, v.y), pack2(v.z, v.w));
    }
    for (int i = g; i < 262144; i += gsz) {   // objects
        float4 v = ((const float4*)objects)[i];
        ((uint2*)objB)[i] = make_uint2(pack2(v.x, v.y), pack2(v.z, v.w));
    }
    for (int i = g; i < 16384; i += gsz) {    // context
        float4 v = ((const float4*)context)[i];
        ((uint2*)ctxB)[i] = make_uint2(pack2(v.x, v.y), pack2(v.z, v.w));
    }
    for (int i = g; i < 131072; i += gsz) {   // spatial
        float4 v = ((const float4*)spatial)[i];
        ((uint2*)spatB)[i] = make_uint2(pack2(v.x, v.y), pack2(v.z, v.w));
    }
    for (int i = g; i < 32256; i += gsz) {    // zero Hp/HoF/Yh/Zo (was memset)
        f32x4 z = {0.f, 0.f, 0.f, 0.f};
        ((f32x4*)zeroWS)[i] = z;
    }
    for (int i = g; i < 512 * 32; i += gsz) {
        int n = i >> 5, k = i & 31;
        WspatT[i] = f2b(Wspat[k * 512 + n]);
    }
    for (int i = g; i < 32 * 512; i += gsz) {
        int n = i >> 9, k = i & 511;
        WrefT[i] = (n < 29) ? f2b(Wref[k * 29 + n]) : (u16)0;
        WattT[i] = (n < 29) ? f2b(Watt[k * 29 + n]) : (u16)0;
    }
    for (int i = g; i < 32 * 2048; i += gsz) {
        int n = i >> 11, k = i & 2047;
        WgT[i] = (n < 29) ? f2b(Wg[k * 29 + n]) : (u16)0;
    }
}

// depth-4 K=1024 main loop: preload 4 k-steps, 7x4 steady, 4-step epilogue.
// 16 loads in flight/wave -> ~310cy latency budget (vs 156 at depth-2).
#define K1024_D4_LOOP(AP0, AP1, BP0, BP1)                                       \
    s16x8 bA0[4], bA1[4], bB0[4], bB1[4];                                       \
    _Pragma("unroll")                                                           \
    for (int s = 0; s < 4; s++) {                                               \
        bA0[s] = *(const s16x8*)(AP0 + s * 32);                                 \
        bA1[s] = *(const s16x8*)(AP1 + s * 32);                                 \
        bB0[s] = *(const s16x8*)(BP0 + s * 32);                                 \
        bB1[s] = *(const s16x8*)(BP1 + s * 32);                                 \
    }                                                                           \
    AP0 += 128; AP1 += 128; BP0 += 128; BP1 += 128;                             \
    for (int it = 0; it < 7; it++) {                                            \
        _Pragma("unroll")                                                       \
        for (int s = 0; s < 4; s++) {                                           \
            s16x8 tA0 = *(const s16x8*)AP0; AP0 += 32;                          \
            s16x8 tA1 = *(const s16x8*)AP1; AP1 += 32;                          \
            s16x8 tB0 = *(const s16x8*)BP0; BP0 += 32;                          \
            s16x8 tB1 = *(const s16x8*)BP1; BP1 += 32;                          \
            acc00 = __builtin_amdgcn_mfma_f32_16x16x32_bf16(bA0[s], bB0[s], acc00, 0, 0, 0); \
            acc01 = __builtin_amdgcn_mfma_f32_16x16x32_bf16(bA0[s], bB1[s], acc01, 0, 0, 0); \
            acc10 = __builtin_amdgcn_mfma_f32_16x16x32_bf16(bA1[s], bB0[s], acc10, 0, 0, 0); \
            acc11 = __builtin_amdgcn_mfma_f32_16x16x32_bf16(bA1[s], bB1[s], acc11, 0, 0, 0); \
            bA0[s] = tA0; bA1[s] = tA1; bB0[s] = tB0; bB1[s] = tB1;             \
        }                                                                       \
    }                                                                           \
    _Pragma("unroll")                                                           \
    for (int s = 0; s < 4; s++) {                                               \
        acc00 = __builtin_amdgcn_mfma_f32_16x16x32_bf16(bA0[s], bB0[s], acc00, 0, 0, 0); \
        acc01 = __builtin_amdgcn_mfma_f32_16x16x32_bf16(bA0[s], bB1[s], acc01, 0, 0, 0); \
        acc10 = __builtin_amdgcn_mfma_f32_16x16x32_bf16(bA1[s], bB0[s], acc10, 0, 0, 0); \
        acc11 = __builtin_amdgcn_mfma_f32_16x16x32_bf16(bA1[s], bB1[s], acc11, 0, 0, 0); \
    }

// ---------------- fused post-prep GEMMs (flat 888-block grid) ---------------
// XCD-bijective swizzle (888 = 8*111): logical-consecutive bids co-located on
// one XCD so the 8 n-tiles sharing an A-panel hit that XCD's L2.
// [0,264):   Pp/Po/Pc = {peoB,objB,ctxB} @ WvisT  (64x64, depth-4 pipeline)
// [264,760): Yh/Zo relu-projection, 64x64 tiles (atomicAdd)
// [760,888): Hp/HoF split-K (atomicAdd, fully preloaded)
__global__ __launch_bounds__(256) void fused_gemms(
    const u16* __restrict__ peoB, const u16* __restrict__ objB,
    const u16* __restrict__ ctxB, const u16* __restrict__ WvisT,
    const u16* __restrict__ WhoT, const float* __restrict__ Who_b,
    const u16* __restrict__ WohT, const float* __restrict__ Woh_b,
    const u16* __restrict__ WgT,
    u16* __restrict__ Pp, u16* __restrict__ Po, u16* __restrict__ Pc,
    float* __restrict__ Yh, float* __restrict__ Zo,
    float* __restrict__ Hp, float* __restrict__ HoF)
{
    __shared__ u16 T[64][72];
    int b0 = blockIdx.x;
    int bid = (b0 & 7) * 111 + (b0 >> 3);   // bijective XCD swizzle, 888=8*111
    int t = threadIdx.x;
    int lane = t & 63, w = t >> 6;
    int l16 = lane & 15, q = lane >> 4;
    int wy = w >> 1, wx = w & 1;

    if (bid < 264) {
        // ---------------- gemm3: 64x64 tile, K=1024 ----------------
        int bx = bid & 7, ty = bid >> 3;
        const u16* A; u16* outB; int koff, bm;
        if (ty < 16)      { A = peoB; outB = Pp; koff = 0;    bm = ty * 64; }
        else if (ty < 32) { A = objB; outB = Po; koff = 1024; bm = (ty - 16) * 64; }
        else              { A = ctxB; outB = Pc; koff = 2048; bm = 0; }
        int bn = bx * 64;

        const u16* ap0 = A + (size_t)(bm + wy * 32 + l16) * 1024 + q * 8;
        const u16* ap1 = ap0 + (size_t)16 * 1024;
        const u16* bp0 = WvisT + (size_t)(bn + wx * 32 + l16) * 3072 + koff + q * 8;
        const u16* bp1 = bp0 + (size_t)16 * 3072;

        f32x4 acc00 = {0,0,0,0}, acc01 = {0,0,0,0}, acc10 = {0,0,0,0}, acc11 = {0,0,0,0};
        K1024_D4_LOOP(ap0, ap1, bp0, bp1)

        f32x4 accs[2][2] = {{acc00, acc01}, {acc10, acc11}};
#pragma unroll
        for (int ii = 0; ii < 2; ii++)
#pragma unroll
            for (int jj = 0; jj < 2; jj++) {
                int col = bn + wx * 32 + jj * 16 + l16;
#pragma unroll
                for (int r = 0; r < 4; r++) {
                    int row = bm + wy * 32 + ii * 16 + q * 4 + r;
                    outB[(size_t)row * 512 + col] = f2b(accs[ii][jj][r]);
                }
            }
    } else if (bid < 760) {
        // ---------------- relu-projection: 64 rows x 64-col chunk ----------
        int r3 = bid - 264;
        int z, rt, nbt;
        if (r3 < 256) { z = 0; rt = r3 >> 4; nbt = r3 & 15; }
        else          { z = 1; r3 -= 256; rt = r3 >> 4; nbt = r3 & 15; }
        const u16* A    = z ? objB : peoB;
        const u16* W1T  = z ? WohT : WhoT;
        const float* bb = z ? Woh_b : Who_b;
        const u16* Wg2  = z ? WgT : WgT + 1024;
        float* U        = z ? Zo : Yh;
        int m0 = rt * 64, nb = nbt * 64;

        int r0 = m0 + wy * 32 + l16;
        int r1 = r0 + 16;
        if (z) { r0 = (r0 / 15) * 16 + (r0 % 15) + 1;
                 r1 = (r1 / 15) * 16 + (r1 % 15) + 1; }
        const u16* ap0 = A + (size_t)r0 * 1024 + q * 8;
        const u16* ap1 = A + (size_t)r1 * 1024 + q * 8;
        const u16* bp0 = W1T + (size_t)(nb + wx * 32 + l16) * 1024 + q * 8;
        const u16* bp1 = bp0 + (size_t)16 * 1024;

        f32x4 acc00 = {0,0,0,0}, acc01 = {0,0,0,0}, acc10 = {0,0,0,0}, acc11 = {0,0,0,0};
        K1024_D4_LOOP(ap0, ap1, bp0, bp1)

        // bias + relu -> T (cols partitioned across nb-blocks: bias added once)
        f32x4 accs[2][2] = {{acc00, acc01}, {acc10, acc11}};
#pragma unroll
        for (int ii = 0; ii < 2; ii++)
#pragma unroll
            for (int jj = 0; jj < 2; jj++) {
                int col = wx * 32 + jj * 16 + l16;
                float bv = bb[nb + col];
#pragma unroll
                for (int rr = 0; rr < 4; rr++) {
                    float v = accs[ii][jj][rr] + bv;
                    T[wy * 32 + ii * 16 + q * 4 + rr][col] = f2b(fmaxf(v, 0.f));
                }
            }
        __syncthreads();

        // stage 2: U_part[64x32] = T(64x64) @ Wg2[nb:nb+64, :32]; wave strip 16 rows
        f32x4 s20 = {0,0,0,0}, s21 = {0,0,0,0};
#pragma unroll
        for (int kk = 0; kk < 64; kk += 32) {
            s16x8 a2 = *(const s16x8*)(&T[w * 16 + l16][kk + q * 8]);
            s16x8 b20 = *(const s16x8*)(Wg2 + (size_t)l16 * 2048 + nb + kk + q * 8);
            s16x8 b21 = *(const s16x8*)(Wg2 + (size_t)(16 + l16) * 2048 + nb + kk + q * 8);
            s20 = __builtin_amdgcn_mfma_f32_16x16x32_bf16(a2, b20, s20, 0, 0, 0);
            s21 = __builtin_amdgcn_mfma_f32_16x16x32_bf16(a2, b21, s21, 0, 0, 0);
        }
#pragma unroll
        for (int rr = 0; rr < 4; rr++) {
            int row = m0 + w * 16 + q * 4 + rr;
            atomicAdd(&U[(size_t)row * 32 + l16], s20[rr]);
            atomicAdd(&U[(size_t)row * 32 + 16 + l16], s21[rr]);
        }
    } else {
        // ---------------- bt32 split-K: 128 rows, 128-k chunk ----------------
        // Only 4 k-steps: fully preload all 16 loads, then 16 MFMAs.
        int r3 = bid - 760;
        int bx = r3 & 7, by = (r3 >> 3) & 7, z = r3 >> 6;
        const u16* A  = z ? objB : peoB;
        const u16* BT = z ? WgT + 1024 : WgT;
        float* outF   = z ? HoF : Hp;
        int bm = bx * 128 + w * 32;
        int kb = by * 128;
        const u16* ap0 = A + (size_t)(bm + l16) * 1024 + kb + q * 8;
        const u16* ap1 = A + (size_t)(bm + 16 + l16) * 1024 + kb + q * 8;
        const u16* bp0 = BT + (size_t)l16 * 2048 + kb + q * 8;
        const u16* bp1 = BT + (size_t)(16 + l16) * 2048 + kb + q * 8;
        f32x4 acc00 = {0,0,0,0}, acc01 = {0,0,0,0}, acc10 = {0,0,0,0}, acc11 = {0,0,0,0};
        s16x8 bA0[4], bA1[4], bB0[4], bB1[4];
#pragma unroll
        for (int s = 0; s < 4; s++) {
            bA0[s] = *(const s16x8*)(ap0 + s * 32);
            bA1[s] = *(const s16x8*)(ap1 + s * 32);
            bB0[s] = *(const s16x8*)(bp0 + s * 32);
            bB1[s] = *(const s16x8*)(bp1 + s * 32);
        }
#pragma unroll
        for (int s = 0; s < 4; s++) {
            acc00 = __builtin_amdgcn_mfma_f32_16x16x32_bf16(bA0[s], bB0[s], acc00, 0, 0, 0);
            acc01 = __builtin_amdgcn_mfma_f32_16x16x32_bf16(bA0[s], bB1[s], acc01, 0, 0, 0);
            acc10 = __builtin_amdgcn_mfma_f32_16x16x32_bf16(bA1[s], bB0[s], acc10, 0, 0, 0);
            acc11 = __builtin_amdgcn_mfma_f32_16x16x32_bf16(bA1[s], bB1[s], acc11, 0, 0, 0);
        }
        f32x4 accs[2][2] = {{acc00, acc01}, {acc10, acc11}};
#pragma unroll
        for (int ii = 0; ii < 2; ii++)
#pragma unroll
            for (int jj = 0; jj < 2; jj++)
#pragma unroll
                for (int r = 0; r < 4; r++)
                    atomicAdd(&outF[(size_t)(bm + ii * 16 + q * 4 + r) * 32 + jj * 16 + l16],
                              accs[ii][jj][r]);
    }
}

// ---- mega: per 32-row tile: aho(MFMA) -> p_att -> fref(in-place LDS)+i_ho -> p_ref
__global__ __launch_bounds__(256) void mega(
    const u16* __restrict__ spatB, const u16* __restrict__ WspatT,
    const float* __restrict__ bspat,
    const u16* __restrict__ Pp, const u16* __restrict__ Po,
    const u16* __restrict__ Pc, const float* __restrict__ bvis,
    const u16* __restrict__ WrefT, const float* __restrict__ bref,
    const u16* __restrict__ WattT, const float* __restrict__ batt,
    const float* __restrict__ wip, const float* __restrict__ bip,
    float* __restrict__ outI, float* __restrict__ outRef,
    float* __restrict__ outAtt, float* __restrict__ adjw)
{
    __shared__ u16 tile[32][512];
    __shared__ float part[32][8];
    __shared__ float wipS[512];
    int t = threadIdx.x;
    int b0 = blockIdx.x;
    int bid = (b0 & 7) * 64 + (b0 >> 3);    // bijective XCD swizzle, 512=8*64
    int c0 = bid * 32;
    int lane = t & 63, w = t >> 6;
    int l16 = lane & 15, q = lane >> 4;

    {
        float2 u = *(const float2*)(wip + t * 2);
        wipS[t * 2]     = u.x;
        wipS[t * 2 + 1] = u.y;
    }

    // step 1: aho rows c0..c0+31; wave w owns cols [w*128, w*128+128)
    {
        s16x8 a0 = *(const s16x8*)(spatB + (size_t)(c0 + l16) * 32 + q * 8);
        s16x8 a1 = *(const s16x8*)(spatB + (size_t)(c0 + 16 + l16) * 32 + q * 8);
        const u16* wb = WspatT + (size_t)(w * 128 + l16) * 32 + q * 8;
        s16x8 cb = *(const s16x8*)wb;
        s16x8 nb_ = *(const s16x8*)(wb + 16 * 32);
        wb += 32 * 32;
#pragma unroll
        for (int nt = 0; nt < 8; nt++) {
            s16x8 tb;
            if (nt < 6) { tb = *(const s16x8*)wb; wb += 16 * 32; }
            int n = w * 128 + nt * 16;
            f32x4 acc0 = {0,0,0,0}, acc1 = {0,0,0,0};
            acc0 = __builtin_amdgcn_mfma_f32_16x16x32_bf16(a0, cb, acc0, 0, 0, 0);
            acc1 = __builtin_amdgcn_mfma_f32_16x16x32_bf16(a1, cb, acc1, 0, 0, 0);
            cb = nb_; nb_ = tb;
            float bias = bspat[n + l16];
#pragma unroll
            for (int r = 0; r < 4; r++) {
                tile[q * 4 + r][n + l16]      = f2b(fmaxf(acc0[r] + bias, 0.f));
                tile[16 + q * 4 + r][n + l16] = f2b(fmaxf(acc1[r] + bias, 0.f));
            }
        }
    }
    __syncthreads();

    // step 2: p_att = aho @ WattT^T + batt  (depth-4 on W loads)
    {
        int rt = w >> 1, ct = w & 1;
        const u16* bp = WattT + (size_t)(ct * 16 + l16) * 512 + q * 8;
        f32x4 acc = {0,0,0,0};
        s16x8 bw[4];
#pragma unroll
        for (int s = 0; s < 4; s++) bw[s] = *(const s16x8*)(bp + s * 32);
        bp += 128;
        for (int it = 0; it < 3; it++) {
#pragma unroll
            for (int s = 0; s < 4; s++) {
                s16x8 tb = *(const s16x8*)bp; bp += 32;
                s16x8 a = *(const s16x8*)(&tile[rt * 16 + l16][(it * 4 + s) * 32 + q * 8]);
                acc = __builtin_amdgcn_mfma_f32_16x16x32_bf16(a, bw[s], acc, 0, 0, 0);
                bw[s] = tb;
            }
        }
#pragma unroll
        for (int s = 0; s < 4; s++) {
            s16x8 a = *(const s16x8*)(&tile[rt * 16 + l16][(12 + s) * 32 + q * 8]);
            acc = __builtin_amdgcn_mfma_f32_16x16x32_bf16(a, bw[s], acc, 0, 0, 0);
        }
        int col = ct * 16 + l16;
        if (col < 29) {
            float bias = batt[col];
#pragma unroll
            for (int r = 0; r < 4; r++) {
                int row = c0 + rt * 16 + q * 4 + r;
                outAtt[(size_t)row * 29 + col] = acc[r] + bias;
            }
        }
    }
    __syncthreads();

    // step 3: fref = relu(Pp+Po+Pc+bvis) * aho (in-place); i_ho partials
    {
        int row = t >> 3, g = t & 7;
        int c = c0 + row;
        int rp = c >> 4, bimg = c >> 8;
        int ro = bimg * 16 + (c & 15);
        const u16* ppr = Pp + (size_t)rp * 512;
        const u16* por = Po + (size_t)ro * 512;
        const u16* pcr = Pc + (size_t)bimg * 512;
        float ps = 0.f;
#pragma unroll 4
        for (int j = 0; j < 64; j += 2) {
            int col = g * 64 + j;
            unsigned int upp = *(const unsigned int*)(ppr + col);
            unsigned int upo = *(const unsigned int*)(por + col);
            unsigned int upc = *(const unsigned int*)(pcr + col);
            float2 bv = *(const float2*)(bvis + col);
            unsigned int uah = *(const unsigned int*)(&tile[row][col]);
            float fv0 = fmaxf(b2f((u16)(upp & 0xffff)) + b2f((u16)(upo & 0xffff))
                            + b2f((u16)(upc & 0xffff)) + bv.x, 0.f);
            float fv1 = fmaxf(b2f((u16)(upp >> 16)) + b2f((u16)(upo >> 16))
                            + b2f((u16)(upc >> 16)) + bv.y, 0.f);
            float fr0 = fv0 * b2f((u16)(uah & 0xffff));
            float fr1 = fv1 * b2f((u16)(uah >> 16));
            *(unsigned int*)(&tile[row][col]) = pack2(fr0, fr1);
            ps += fr0 * wipS[col] + fr1 * wipS[col + 1];
        }
        part[row][g] = ps;
    }
    __syncthreads();

    if (t < 32) {
        float s = part[t][0] + part[t][1] + part[t][2] + part[t][3]
                + part[t][4] + part[t][5] + part[t][6] + part[t][7] + bip[0];
        outI[c0 + t] = s;
        adjw[c0 + t] = 1.f / (1.f + expf(-s));
    }

    // step 4: p_ref = fref @ WrefT^T + bref  (depth-4 on W loads)
    {
        int rt = w >> 1, ct = w & 1;
        const u16* bp = WrefT + (size_t)(ct * 16 + l16) * 512 + q * 8;
        f32x4 acc = {0,0,0,0};
        s16x8 bw[4];
#pragma unroll
        for (int s = 0; s < 4; s++) bw[s] = *(const s16x8*)(bp + s * 32);
        bp += 128;
        for (int it = 0; it < 3; it++) {
#pragma unroll
            for (int s = 0; s < 4; s++) {
                s16x8 tb = *(const s16x8*)bp; bp += 32;
                s16x8 a = *(const s16x8*)(&tile[rt * 16 + l16][(it * 4 + s) * 32 + q * 8]);
                acc = __builtin_amdgcn_mfma_f32_16x16x32_bf16(a, bw[s], acc, 0, 0, 0);
                bw[s] = tb;
            }
        }
#pragma unroll
        for (int s = 0; s < 4; s++) {
            s16x8 a = *(const s16x8*)(&tile[rt * 16 + l16][(12 + s) * 32 + q * 8]);
            acc = __builtin_amdgcn_mfma_f32_16x16x32_bf16(a, bw[s], acc, 0, 0, 0);
        }
        int col = ct * 16 + l16;
        if (col < 29) {
            float bias = bref[col];
#pragma unroll
            for (int r = 0; r < 4; r++) {
                int row = c0 + rt * 16 + q * 4 + r;
                outRef[(size_t)row * 29 + col] = acc[r] + bias;
            }
        }
    }
}

// ---- p_graph: per image, tiny adj contractions + broadcast sum -------------
__global__ __launch_bounds__(256) void pgraph2(
    const float* __restrict__ adjw, const float* __restrict__ Hp,
    const float* __restrict__ HoF, const float* __restrict__ Yh,
    const float* __restrict__ Zo, const float* __restrict__ bg,
    float* __restrict__ outG)
{
    int b = blockIdx.x, t = threadIdx.x;
    __shared__ float adjS[16][16];
    __shared__ float YhS[16][32];
    __shared__ float ZoS[15][32];
    __shared__ float PA[16][32];
    __shared__ float OA[16][32];
    adjS[t >> 4][t & 15] = adjw[b * 256 + t];
    for (int i = t; i < 512; i += 256)
        YhS[i >> 5][i & 31] = Yh[(size_t)(b * 16 + (i >> 5)) * 32 + (i & 31)];
    for (int i = t; i < 480; i += 256)
        ZoS[i >> 5][i & 31] = Zo[(size_t)(b * 15 + (i >> 5)) * 32 + (i & 31)];
    __syncthreads();
    for (int i = t; i < 512; i += 256) {
        int p = i >> 5, j = i & 31;
        float s = 0.f;
#pragma unroll
        for (int o = 0; o < 15; o++) s += adjS[p][o + 1] * ZoS[o][j];
        PA[p][j] = s;
        float s2 = 0.f;
#pragma unroll
        for (int pp = 0; pp < 16; pp++) s2 += adjS[pp][p] * YhS[pp][j];
        OA[p][j] = s2;
    }
    __syncthreads();
    int p = t >> 4, l = t & 15;
    const float* hp = Hp + (size_t)(b * 16 + p) * 32;
    const float* ho = HoF + (size_t)(b * 16 + l) * 32;
    size_t c = (size_t)b * 256 + t;
    for (int j = 0; j < 29; j++) {
        float v = hp[j] + ho[j] + bg[j] + PA[p][j];
        if (l >= 1) v += OA[l][j];
        outG[c * 29 + j] = v;
    }
}

extern "C" void kernel_launch(void* const* d_in, const int* in_sizes, int n_in,
                              void* d_out, int out_size, void* d_ws, size_t ws_size,
                              hipStream_t stream)
{
    const float* people  = (const float*)d_in[0];
    const float* objects = (const float*)d_in[1];
    const float* context = (const float*)d_in[2];
    const float* spatial = (const float*)d_in[3];
    const float* Wvis_w  = (const float*)d_in[4];
    const float* Wvis_b  = (const float*)d_in[5];
    const float* Wspat_w = (const float*)d_in[6];
    const float* Wspat_b = (const float*)d_in[7];
    const float* Wip_w   = (const float*)d_in[8];
    const float* Wip_b   = (const float*)d_in[9];
    const float* Wref_w  = (const float*)d_in[10];
    const float* Wref_b  = (const float*)d_in[11];
    const float* Watt_w  = (const float*)d_in[12];
    const float* Watt_b  = (const float*)d_in[13];
    const float* Woh_w   = (const float*)d_in[14];
    const float* Woh_b   = (const float*)d_in[15];
    const float* Who_w   = (const float*)d_in[16];
    const float* Who_b   = (const float*)d_in[17];
    const float* Wg_w    = (const float*)d_in[18];
    const float* Wg_b    = (const float*)d_in[19];

    char* ws = (char*)d_ws;
    u16* WspatT = (u16*)(ws + OFF_WSPATT);
    u16* WrefT  = (u16*)(ws + OFF_WREFT);
    u16* WattT  = (u16*)(ws + OFF_WATTT);
    u16* WgT    = (u16*)(ws + OFF_WGT);
    u16* Ppb    = (u16*)(ws + OFF_PP);
    u16* Pob    = (u16*)(ws + OFF_PO);
    u16* Pcb    = (u16*)(ws + OFF_PC);
    float* adjw = (float*)(ws + OFF_ADJ);
    float* Hp   = (float*)(ws + OFF_HP);
    float* HoF  = (float*)(ws + OFF_HOF);
    float* Yh   = (float*)(ws + OFF_YH);
    float* Zo   = (float*)(ws + OFF_ZO);
    u16* WvisT2 = (u16*)(ws + OFF_WVIST2);
    u16* WhoT2  = (u16*)(ws + OFF_WHOT2);
    u16* WohT2  = (u16*)(ws + OFF_WOHT2);
    u16* peoB   = (u16*)(ws + OFF_PEOB);
    u16* objB   = (u16*)(ws + OFF_OBJB);
    u16* ctxB   = (u16*)(ws + OFF_CTXB);
    u16* spatB  = (u16*)(ws + OFF_SPATB);
    float* zeroWS = (float*)(ws + ZERO_OFF);

    float* outI   = (float*)d_out;        // i_ho   [16384]
    float* outRef = outI + 16384;         // p_ref  [16384,29]
    float* outAtt = outI + 491520;        // p_att  [16384,29]
    float* outG   = outI + 966656;        // p_graph[16384,29]

    prep_all<<<1408, 256, 0, stream>>>(people, objects, context, spatial,
        Wvis_w, Who_w, Woh_w, Wspat_w, Wref_w, Watt_w, Wg_w,
        peoB, objB, ctxB, spatB, WvisT2, WhoT2, WohT2,
        WspatT, WrefT, WattT, WgT, zeroWS);

    fused_gemms<<<888, 256, 0, stream>>>(peoB, objB, ctxB, WvisT2,
        WhoT2, Who_b, WohT2, Woh_b, WgT,
        Ppb, Pob, Pcb, Yh, Zo, Hp, HoF);

    mega<<<512, 256, 0, stream>>>(spatB, WspatT, Wspat_b,
                                  Ppb, Pob, Pcb, Wvis_b,
                                  WrefT, Wref_b, WattT, Watt_b,
                                  Wip_w, Wip_b,
                                  outI, outRef, outAtt, adjw);

    pgraph2<<<64, 256, 0, stream>>>(adjw, Hp, HoF, Yh, Zo, Wg_b, outG);
}

// Round 2
// 155.991 us; speedup vs baseline: 1.2796x; 1.2796x over previous
//
#include <hip/hip_runtime.h>

// VSGNet fused pipeline — fp32 in/out, bf16 MFMA compute.
// B=64 P=16 L=16 D=1024 SP=32 PROJ=512 ACT=29, C=16384.
// R10 post-mortem: chunked whole-grid XCD swizzle starved XCD7 (all split-K
// blocks) -> occupancy 29.5->22.2%, dur 50->62.9us. FETCH 21->16MB proved the
// L2-locality mechanism works. Depth-1->2 reg pipeline scaling (72->50us)
// implies effective load latency ~1000cyc: register pipelining can't hide it.
// R11: (1) per-section bijective swizzle (264/496/128, each /8) - locality
// without imbalance; (2) gemm3+relu rewritten as LDS double-buffered 64x64
// tiles, BK=64, reg-staged with depth-2 tile prefetch; [64][72] padding ->
// balanced 8 words/bank on ds_read_b128/ds_write_b128. Whole tile in flight
// per wave, one drain per K-tile. L2-BW floor ~7us for this kernel.

typedef unsigned short u16;   // bf16 bits
typedef short s16x8 __attribute__((ext_vector_type(8)));
typedef float f32x4 __attribute__((ext_vector_type(4)));

__device__ __forceinline__ u16 f2b(float f) {
    union { float f; unsigned int i; } v; v.f = f;
    unsigned int r = (v.i + 0x7fffu + ((v.i >> 16) & 1u)) >> 16;  // RNE
    return (u16)r;
}
__device__ __forceinline__ float b2f(u16 u) {
    union { float f; unsigned int i; } v; v.i = ((unsigned int)u) << 16; return v.f;
}
__device__ __forceinline__ unsigned int pack2(float x, float y) {
    return (unsigned int)f2b(x) | ((unsigned int)f2b(y) << 16);
}

// ---------------- workspace layout (bytes) ----------------
#define OFF_WSPATT 0u         // [512][32]  bf16
#define OFF_WREFT  32768u     // [32][512]  bf16 (rows 29..31 zero)
#define OFF_WATTT  65536u     // [32][512]  bf16
#define OFF_WGT    98304u     // [32][2048] bf16
#define OFF_PP     229376u    // [1024][512] bf16
#define OFF_PO     1277952u   // [1024][512] bf16
#define OFF_PC     2326528u   // [64][512]  bf16
#define OFF_ADJ    2392064u   // [16384] f32
#define OFF_HP     2457600u   // [1024][32] f32
#define OFF_HOF    2588672u   // [1024][32] f32
#define OFF_YH     2719744u   // [1024][32] f32
#define OFF_ZO     2850816u   // [960][32]  f32
#define ZERO_OFF   2457600u
#define ZERO_LEN   516096u
#define OFF_WVIST2 2973696u   // [512][3072] bf16 (n-major, k contiguous)
#define OFF_WHOT2  6119424u   // [1024][1024] bf16
#define OFF_WOHT2  8216576u   // [1024][1024] bf16
#define OFF_PEOB   10313728u  // [1024][1024] bf16
#define OFF_OBJB   12410880u  // [1024][1024] bf16
#define OFF_CTXB   14508032u  // [64][1024]  bf16
#define OFF_SPATB  14639104u  // [16384][32] bf16

// ---------------- prep: LDS-tiled big transposes + vectorized converts ------
// bids [0,896): 64x64 transpose tiles (Who:256, Woh:256, Wvis:384)
// bids [896,1408): grid-stride converts + small head transposes + ws zeroing
__global__ __launch_bounds__(256) void prep_all(
    const float* __restrict__ people, const float* __restrict__ objects,
    const float* __restrict__ context, const float* __restrict__ spatial,
    const float* __restrict__ Wvis, const float* __restrict__ Who,
    const float* __restrict__ Woh, const float* __restrict__ Wspat,
    const float* __restrict__ Wref, const float* __restrict__ Watt,
    const float* __restrict__ Wg,
    u16* __restrict__ peoB, u16* __restrict__ objB, u16* __restrict__ ctxB,
    u16* __restrict__ spatB, u16* __restrict__ WvisT, u16* __restrict__ WhoT,
    u16* __restrict__ WohT, u16* __restrict__ WspatT, u16* __restrict__ WrefT,
    u16* __restrict__ WattT, u16* __restrict__ WgT, float* __restrict__ zeroWS)
{
    __shared__ float S[64][65];
    int bid = blockIdx.x, t = threadIdx.x;
    if (bid < 896) {
        const float* src; u16* dst; int N, K, kt, nt;
        int tb = bid;
        if (tb < 256)      { src = Who;  dst = WhoT;  K = 1024; N = 1024; kt = tb >> 4; nt = tb & 15; }
        else if (tb < 512) { tb -= 256; src = Woh;  dst = WohT;  K = 1024; N = 1024; kt = tb >> 4; nt = tb & 15; }
        else               { tb -= 512; src = Wvis; dst = WvisT; K = 3072; N = 512;  kt = tb >> 3; nt = tb & 7; }
        int k0 = kt * 64, n0 = nt * 64;
        int tx = t & 63, ty = t >> 6;   // 4 rows/pass
#pragma unroll
        for (int i = 0; i < 16; i++)
            S[ty + 4 * i][tx] = src[(size_t)(k0 + ty + 4 * i) * N + n0 + tx];
        __syncthreads();
#pragma unroll
        for (int i = 0; i < 16; i++)
            dst[(size_t)(n0 + ty + 4 * i) * K + k0 + tx] = f2b(S[tx][ty + 4 * i]);
        return;
    }
    int g = (bid - 896) * 256 + t;
    const int gsz = 512 * 256;
    for (int i = g; i < 262144; i += gsz) {   // people (1M floats as float4)
        float4 v = ((const float4*)people)[i];
        ((uint2*)peoB)[i] = make_uint2(pack2(v.x, v.y), pack2(v.z, v.w));
    }
    for (int i = g; i < 262144; i += gsz) {   // objects
        float4 v = ((const float4*)objects)[i];
        ((uint2*)objB)[i] = make_uint2(pack2(v.x, v.y), pack2(v.z, v.w));
    }
    for (int i = g; i < 16384; i += gsz) {    // context
        float4 v = ((const float4*)context)[i];
        ((uint2*)ctxB)[i] = make_uint2(pack2(v.x, v.y), pack2(v.z, v.w));
    }
    for (int i = g; i < 131072; i += gsz) {   // spatial
        float4 v = ((const float4*)spatial)[i];
        ((uint2*)spatB)[i] = make_uint2(pack2(v.x, v.y), pack2(v.z, v.w));
    }
    for (int i = g; i < 32256; i += gsz) {    // zero Hp/HoF/Yh/Zo (was memset)
        f32x4 z = {0.f, 0.f, 0.f, 0.f};
        ((f32x4*)zeroWS)[i] = z;
    }
    for (int i = g; i < 512 * 32; i += gsz) {
        int n = i >> 5, k = i & 31;
        WspatT[i] = f2b(Wspat[k * 512 + n]);
    }
    for (int i = g; i < 32 * 512; i += gsz) {
        int n = i >> 9, k = i & 511;
        WrefT[i] = (n < 29) ? f2b(Wref[k * 29 + n]) : (u16)0;
        WattT[i] = (n < 29) ? f2b(Watt[k * 29 + n]) : (u16)0;
    }
    for (int i = g; i < 32 * 2048; i += gsz) {
        int n = i >> 11, k = i & 2047;
        WgT[i] = (n < 29) ? f2b(Wg[k * 29 + n]) : (u16)0;
    }
}

// ---------------- fused post-prep GEMMs (flat 888-block grid) ---------------
// Per-section bijective XCD swizzle (sections start at multiples of 8 in b0,
// so b0%8 == local%8 == XCD): locality within a section, balance across them.
// [0,264):   Pp/Po/Pc = {peoB,objB,ctxB} @ WvisT  (LDS dbuf 64x64)
// [264,760): Yh/Zo relu-projection (LDS dbuf 64x64 + stage2 atomics)
// [760,888): Hp/HoF split-K (atomicAdd, fully preloaded)
__global__ __launch_bounds__(256) void fused_gemms(
    const u16* __restrict__ peoB, const u16* __restrict__ objB,
    const u16* __restrict__ ctxB, const u16* __restrict__ WvisT,
    const u16* __restrict__ WhoT, const float* __restrict__ Who_b,
    const u16* __restrict__ WohT, const float* __restrict__ Woh_b,
    const u16* __restrict__ WgT,
    u16* __restrict__ Pp, u16* __restrict__ Po, u16* __restrict__ Pc,
    float* __restrict__ Yh, float* __restrict__ Zo,
    float* __restrict__ Hp, float* __restrict__ HoF)
{
    // double-buffered K-tiles; [64][72] padding: row stride 144B = 36 banks
    // -> ds_read_b128/ds_write_b128 land balanced 8 words/bank (minimum).
    __shared__ __align__(16) u16 As[2][64][72];
    __shared__ __align__(16) u16 Bs[2][64][72];

    int b0 = blockIdx.x, bid;
    if (b0 < 264)      bid = (b0 & 7) * 33 + (b0 >> 3);
    else if (b0 < 760) { int l = b0 - 264; bid = 264 + (l & 7) * 62 + (l >> 3); }
    else               { int l = b0 - 760; bid = 760 + (l & 7) * 16 + (l >> 3); }
    int t = threadIdx.x;
    int lane = t & 63, w = t >> 6;
    int l16 = lane & 15, q = lane >> 4;
    int wy = w >> 1, wx = w & 1;

    if (bid < 760) {
        // ---------- unified LDS-staged 64x64 tile, K=1024, BK=64 ----------
        const u16 *Ap, *Bp;
        int Bstride, bm, bn, koff = 0, zrm = 0;
        u16* outB = nullptr;
        const float* bb = nullptr; const u16* Wg2 = nullptr; float* U = nullptr;
        if (bid < 264) {
            int bx = bid & 7, ty = bid >> 3;
            if (ty < 16)      { Ap = peoB; outB = Pp; koff = 0;    bm = ty * 64; }
            else if (ty < 32) { Ap = objB; outB = Po; koff = 1024; bm = (ty - 16) * 64; }
            else              { Ap = ctxB; outB = Pc; koff = 2048; bm = 0; }
            bn = bx * 64;
            Bp = WvisT; Bstride = 3072;
        } else {
            int r3 = bid - 264;
            int zz, rt, nbt;
            if (r3 < 256) { zz = 0; rt = r3 >> 4; nbt = r3 & 15; }
            else          { zz = 1; r3 -= 256; rt = r3 >> 4; nbt = r3 & 15; }
            zrm = zz;
            Ap = zz ? objB : peoB;
            Bp = zz ? WohT : WhoT; Bstride = 1024;
            bb = zz ? Woh_b : Who_b;
            Wg2 = zz ? WgT : WgT + 1024;
            U = zz ? Zo : Yh;
            bm = rt * 64; bn = nbt * 64;
        }

        // staging coords: thread t owns rows {tr, 32+tr}, 8 k-cols at tc
        int tr = t >> 3, tc = (t & 7) * 8;
        int a0r = bm + tr, a1r = bm + 32 + tr;
        if (zrm) { a0r = (a0r / 15) * 16 + (a0r % 15) + 1;   // skip no-object slot
                   a1r = (a1r / 15) * 16 + (a1r % 15) + 1; }
        const u16* gA0 = Ap + (size_t)a0r * 1024 + tc;
        const u16* gA1 = Ap + (size_t)a1r * 1024 + tc;
        const u16* gB0 = Bp + (size_t)(bn + tr) * Bstride + koff + tc;
        const u16* gB1 = Bp + (size_t)(bn + 32 + tr) * Bstride + koff + tc;

        // prologue: tile0 -> buf0; tile1 -> regs
        s16x8 rA0 = *(const s16x8*)gA0, rA1 = *(const s16x8*)gA1;
        s16x8 rB0 = *(const s16x8*)gB0, rB1 = *(const s16x8*)gB1;
        gA0 += 64; gA1 += 64; gB0 += 64; gB1 += 64;
        *(s16x8*)&As[0][tr][tc]      = rA0;
        *(s16x8*)&As[0][32 + tr][tc] = rA1;
        *(s16x8*)&Bs[0][tr][tc]      = rB0;
        *(s16x8*)&Bs[0][32 + tr][tc] = rB1;
        rA0 = *(const s16x8*)gA0; rA1 = *(const s16x8*)gA1;
        rB0 = *(const s16x8*)gB0; rB1 = *(const s16x8*)gB1;
        gA0 += 64; gA1 += 64; gB0 += 64; gB1 += 64;
        __syncthreads();

        f32x4 acc00 = {0,0,0,0}, acc01 = {0,0,0,0}, acc10 = {0,0,0,0}, acc11 = {0,0,0,0};
        int cur = 0;
        for (int kt = 0; kt < 16; kt++) {
#pragma unroll
            for (int kk = 0; kk < 2; kk++) {
                s16x8 a0 = *(const s16x8*)&As[cur][wy * 32 + l16][kk * 32 + q * 8];
                s16x8 a1 = *(const s16x8*)&As[cur][wy * 32 + 16 + l16][kk * 32 + q * 8];
                s16x8 b0 = *(const s16x8*)&Bs[cur][wx * 32 + l16][kk * 32 + q * 8];
                s16x8 b1 = *(const s16x8*)&Bs[cur][wx * 32 + 16 + l16][kk * 32 + q * 8];
                acc00 = __builtin_amdgcn_mfma_f32_16x16x32_bf16(a0, b0, acc00, 0, 0, 0);
                acc01 = __builtin_amdgcn_mfma_f32_16x16x32_bf16(a0, b1, acc01, 0, 0, 0);
                acc10 = __builtin_amdgcn_mfma_f32_16x16x32_bf16(a1, b0, acc10, 0, 0, 0);
                acc11 = __builtin_amdgcn_mfma_f32_16x16x32_bf16(a1, b1, acc11, 0, 0, 0);
            }
            if (kt < 15) {
                __syncthreads();                      // everyone done reading cur
                *(s16x8*)&As[cur ^ 1][tr][tc]      = rA0;
                *(s16x8*)&As[cur ^ 1][32 + tr][tc] = rA1;
                *(s16x8*)&Bs[cur ^ 1][tr][tc]      = rB0;
                *(s16x8*)&Bs[cur ^ 1][32 + tr][tc] = rB1;
                if (kt < 14) {                        // prefetch tile kt+2
                    rA0 = *(const s16x8*)gA0; rA1 = *(const s16x8*)gA1;
                    rB0 = *(const s16x8*)gB0; rB1 = *(const s16x8*)gB1;
                    gA0 += 64; gA1 += 64; gB0 += 64; gB1 += 64;
                }
                __syncthreads();                      // next buf ready
                cur ^= 1;
            }
        }

        f32x4 accs[2][2] = {{acc00, acc01}, {acc10, acc11}};
        if (bid < 264) {
            // gemm3 epilogue: bf16 store
#pragma unroll
            for (int ii = 0; ii < 2; ii++)
#pragma unroll
                for (int jj = 0; jj < 2; jj++) {
                    int col = bn + wx * 32 + jj * 16 + l16;
#pragma unroll
                    for (int r = 0; r < 4; r++) {
                        int row = bm + wy * 32 + ii * 16 + q * 4 + r;
                        outB[(size_t)row * 512 + col] = f2b(accs[ii][jj][r]);
                    }
                }
        } else {
            // relu epilogue: bias+relu -> T (reuse As[0]; last compute read buf1)
            u16 (*T)[72] = As[0];
#pragma unroll
            for (int ii = 0; ii < 2; ii++)
#pragma unroll
                for (int jj = 0; jj < 2; jj++) {
                    int col = wx * 32 + jj * 16 + l16;
                    float bv = bb[bn + col];
#pragma unroll
                    for (int rr = 0; rr < 4; rr++) {
                        float v = accs[ii][jj][rr] + bv;
                        T[wy * 32 + ii * 16 + q * 4 + rr][col] = f2b(fmaxf(v, 0.f));
                    }
                }
            __syncthreads();

            // stage 2: U_part[64x32] = T(64x64) @ Wg2[bn:bn+64, :32]
            f32x4 s20 = {0,0,0,0}, s21 = {0,0,0,0};
#pragma unroll
            for (int kk = 0; kk < 64; kk += 32) {
                s16x8 a2 = *(const s16x8*)(&T[w * 16 + l16][kk + q * 8]);
                s16x8 b20 = *(const s16x8*)(Wg2 + (size_t)l16 * 2048 + bn + kk + q * 8);
                s16x8 b21 = *(const s16x8*)(Wg2 + (size_t)(16 + l16) * 2048 + bn + kk + q * 8);
                s20 = __builtin_amdgcn_mfma_f32_16x16x32_bf16(a2, b20, s20, 0, 0, 0);
                s21 = __builtin_amdgcn_mfma_f32_16x16x32_bf16(a2, b21, s21, 0, 0, 0);
            }
#pragma unroll
            for (int rr = 0; rr < 4; rr++) {
                int row = bm + w * 16 + q * 4 + rr;
                atomicAdd(&U[(size_t)row * 32 + l16], s20[rr]);
                atomicAdd(&U[(size_t)row * 32 + 16 + l16], s21[rr]);
            }
        }
    } else {
        // ---------------- bt32 split-K: 128 rows, 128-k chunk ----------------
        // Only 4 k-steps: fully preload all 16 loads, then 16 MFMAs.
        int r3 = bid - 760;
        int bx = r3 & 7, by = (r3 >> 3) & 7, z = r3 >> 6;
        const u16* A  = z ? objB : peoB;
        const u16* BT = z ? WgT + 1024 : WgT;
        float* outF   = z ? HoF : Hp;
        int bm = bx * 128 + w * 32;
        int kb = by * 128;
        const u16* ap0 = A + (size_t)(bm + l16) * 1024 + kb + q * 8;
        const u16* ap1 = A + (size_t)(bm + 16 + l16) * 1024 + kb + q * 8;
        const u16* bp0 = BT + (size_t)l16 * 2048 + kb + q * 8;
        const u16* bp1 = BT + (size_t)(16 + l16) * 2048 + kb + q * 8;
        f32x4 acc00 = {0,0,0,0}, acc01 = {0,0,0,0}, acc10 = {0,0,0,0}, acc11 = {0,0,0,0};
        s16x8 bA0[4], bA1[4], bB0[4], bB1[4];
#pragma unroll
        for (int s = 0; s < 4; s++) {
            bA0[s] = *(const s16x8*)(ap0 + s * 32);
            bA1[s] = *(const s16x8*)(ap1 + s * 32);
            bB0[s] = *(const s16x8*)(bp0 + s * 32);
            bB1[s] = *(const s16x8*)(bp1 + s * 32);
        }
#pragma unroll
        for (int s = 0; s < 4; s++) {
            acc00 = __builtin_amdgcn_mfma_f32_16x16x32_bf16(bA0[s], bB0[s], acc00, 0, 0, 0);
            acc01 = __builtin_amdgcn_mfma_f32_16x16x32_bf16(bA0[s], bB1[s], acc01, 0, 0, 0);
            acc10 = __builtin_amdgcn_mfma_f32_16x16x32_bf16(bA1[s], bB0[s], acc10, 0, 0, 0);
            acc11 = __builtin_amdgcn_mfma_f32_16x16x32_bf16(bA1[s], bB1[s], acc11, 0, 0, 0);
        }
        f32x4 accs[2][2] = {{acc00, acc01}, {acc10, acc11}};
#pragma unroll
        for (int ii = 0; ii < 2; ii++)
#pragma unroll
            for (int jj = 0; jj < 2; jj++)
#pragma unroll
                for (int r = 0; r < 4; r++)
                    atomicAdd(&outF[(size_t)(bm + ii * 16 + q * 4 + r) * 32 + jj * 16 + l16],
                              accs[ii][jj][r]);
    }
}

// ---- mega: per 32-row tile: aho(MFMA) -> p_att -> fref(in-place LDS)+i_ho -> p_ref
__global__ __launch_bounds__(256) void mega(
    const u16* __restrict__ spatB, const u16* __restrict__ WspatT,
    const float* __restrict__ bspat,
    const u16* __restrict__ Pp, const u16* __restrict__ Po,
    const u16* __restrict__ Pc, const float* __restrict__ bvis,
    const u16* __restrict__ WrefT, const float* __restrict__ bref,
    const u16* __restrict__ WattT, const float* __restrict__ batt,
    const float* __restrict__ wip, const float* __restrict__ bip,
    float* __restrict__ outI, float* __restrict__ outRef,
    float* __restrict__ outAtt, float* __restrict__ adjw)
{
    __shared__ u16 tile[32][512];
    __shared__ float part[32][8];
    __shared__ float wipS[512];
    int t = threadIdx.x;
    int b0 = blockIdx.x;
    int bid = (b0 & 7) * 64 + (b0 >> 3);    // bijective XCD swizzle, 512=8*64
    int c0 = bid * 32;
    int lane = t & 63, w = t >> 6;
    int l16 = lane & 15, q = lane >> 4;

    {
        float2 u = *(const float2*)(wip + t * 2);
        wipS[t * 2]     = u.x;
        wipS[t * 2 + 1] = u.y;
    }

    // step 1: aho rows c0..c0+31; wave w owns cols [w*128, w*128+128)
    {
        s16x8 a0 = *(const s16x8*)(spatB + (size_t)(c0 + l16) * 32 + q * 8);
        s16x8 a1 = *(const s16x8*)(spatB + (size_t)(c0 + 16 + l16) * 32 + q * 8);
        const u16* wb = WspatT + (size_t)(w * 128 + l16) * 32 + q * 8;
        s16x8 cb = *(const s16x8*)wb;
        s16x8 nb_ = *(const s16x8*)(wb + 16 * 32);
        wb += 32 * 32;
#pragma unroll
        for (int nt = 0; nt < 8; nt++) {
            s16x8 tb;
            if (nt < 6) { tb = *(const s16x8*)wb; wb += 16 * 32; }
            int n = w * 128 + nt * 16;
            f32x4 acc0 = {0,0,0,0}, acc1 = {0,0,0,0};
            acc0 = __builtin_amdgcn_mfma_f32_16x16x32_bf16(a0, cb, acc0, 0, 0, 0);
            acc1 = __builtin_amdgcn_mfma_f32_16x16x32_bf16(a1, cb, acc1, 0, 0, 0);
            cb = nb_; nb_ = tb;
            float bias = bspat[n + l16];
#pragma unroll
            for (int r = 0; r < 4; r++) {
                tile[q * 4 + r][n + l16]      = f2b(fmaxf(acc0[r] + bias, 0.f));
                tile[16 + q * 4 + r][n + l16] = f2b(fmaxf(acc1[r] + bias, 0.f));
            }
        }
    }
    __syncthreads();

    // step 2: p_att = aho @ WattT^T + batt  (depth-4 on W loads)
    {
        int rt = w >> 1, ct = w & 1;
        const u16* bp = WattT + (size_t)(ct * 16 + l16) * 512 + q * 8;
        f32x4 acc = {0,0,0,0};
        s16x8 bw[4];
#pragma unroll
        for (int s = 0; s < 4; s++) bw[s] = *(const s16x8*)(bp + s * 32);
        bp += 128;
        for (int it = 0; it < 3; it++) {
#pragma unroll
            for (int s = 0; s < 4; s++) {
                s16x8 tb = *(const s16x8*)bp; bp += 32;
                s16x8 a = *(const s16x8*)(&tile[rt * 16 + l16][(it * 4 + s) * 32 + q * 8]);
                acc = __builtin_amdgcn_mfma_f32_16x16x32_bf16(a, bw[s], acc, 0, 0, 0);
                bw[s] = tb;
            }
        }
#pragma unroll
        for (int s = 0; s < 4; s++) {
            s16x8 a = *(const s16x8*)(&tile[rt * 16 + l16][(12 + s) * 32 + q * 8]);
            acc = __builtin_amdgcn_mfma_f32_16x16x32_bf16(a, bw[s], acc, 0, 0, 0);
        }
        int col = ct * 16 + l16;
        if (col < 29) {
            float bias = batt[col];
#pragma unroll
            for (int r = 0; r < 4; r++) {
                int row = c0 + rt * 16 + q * 4 + r;
                outAtt[(size_t)row * 29 + col] = acc[r] + bias;
            }
        }
    }
    __syncthreads();

    // step 3: fref = relu(Pp+Po+Pc+bvis) * aho (in-place); i_ho partials
    {
        int row = t >> 3, g = t & 7;
        int c = c0 + row;
        int rp = c >> 4, bimg = c >> 8;
        int ro = bimg * 16 + (c & 15);
        const u16* ppr = Pp + (size_t)rp * 512;
        const u16* por = Po + (size_t)ro * 512;
        const u16* pcr = Pc + (size_t)bimg * 512;
        float ps = 0.f;
#pragma unroll 4
        for (int j = 0; j < 64; j += 2) {
            int col = g * 64 + j;
            unsigned int upp = *(const unsigned int*)(ppr + col);
            unsigned int upo = *(const unsigned int*)(por + col);
            unsigned int upc = *(const unsigned int*)(pcr + col);
            float2 bv = *(const float2*)(bvis + col);
            unsigned int uah = *(const unsigned int*)(&tile[row][col]);
            float fv0 = fmaxf(b2f((u16)(upp & 0xffff)) + b2f((u16)(upo & 0xffff))
                            + b2f((u16)(upc & 0xffff)) + bv.x, 0.f);
            float fv1 = fmaxf(b2f((u16)(upp >> 16)) + b2f((u16)(upo >> 16))
                            + b2f((u16)(upc >> 16)) + bv.y, 0.f);
            float fr0 = fv0 * b2f((u16)(uah & 0xffff));
            float fr1 = fv1 * b2f((u16)(uah >> 16));
            *(unsigned int*)(&tile[row][col]) = pack2(fr0, fr1);
            ps += fr0 * wipS[col] + fr1 * wipS[col + 1];
        }
        part[row][g] = ps;
    }
    __syncthreads();

    if (t < 32) {
        float s = part[t][0] + part[t][1] + part[t][2] + part[t][3]
                + part[t][4] + part[t][5] + part[t][6] + part[t][7] + bip[0];
        outI[c0 + t] = s;
        adjw[c0 + t] = 1.f / (1.f + expf(-s));
    }

    // step 4: p_ref = fref @ WrefT^T + bref  (depth-4 on W loads)
    {
        int rt = w >> 1, ct = w & 1;
        const u16* bp = WrefT + (size_t)(ct * 16 + l16) * 512 + q * 8;
        f32x4 acc = {0,0,0,0};
        s16x8 bw[4];
#pragma unroll
        for (int s = 0; s < 4; s++) bw[s] = *(const s16x8*)(bp + s * 32);
        bp += 128;
        for (int it = 0; it < 3; it++) {
#pragma unroll
            for (int s = 0; s < 4; s++) {
                s16x8 tb = *(const s16x8*)bp; bp += 32;
                s16x8 a = *(const s16x8*)(&tile[rt * 16 + l16][(it * 4 + s) * 32 + q * 8]);
                acc = __builtin_amdgcn_mfma_f32_16x16x32_bf16(a, bw[s], acc, 0, 0, 0);
                bw[s] = tb;
            }
        }
#pragma unroll
        for (int s = 0; s < 4; s++) {
            s16x8 a = *(const s16x8*)(&tile[rt * 16 + l16][(12 + s) * 32 + q * 8]);
            acc = __builtin_amdgcn_mfma_f32_16x16x32_bf16(a, bw[s], acc, 0, 0, 0);
        }
        int col = ct * 16 + l16;
        if (col < 29) {
            float bias = bref[col];
#pragma unroll
            for (int r = 0; r < 4; r++) {
                int row = c0 + rt * 16 + q * 4 + r;
                outRef[(size_t)row * 29 + col] = acc[r] + bias;
            }
        }
    }
}

// ---- p_graph: per image, tiny adj contractions + broadcast sum -------------
__global__ __launch_bounds__(256) void pgraph2(
    const float* __restrict__ adjw, const float* __restrict__ Hp,
    const float* __restrict__ HoF, const float* __restrict__ Yh,
    const float* __restrict__ Zo, const float* __restrict__ bg,
    float* __restrict__ outG)
{
    int b = blockIdx.x, t = threadIdx.x;
    __shared__ float adjS[16][16];
    __shared__ float YhS[16][32];
    __shared__ float ZoS[15][32];
    __shared__ float PA[16][32];
    __shared__ float OA[16][32];
    adjS[t >> 4][t & 15] = adjw[b * 256 + t];
    for (int i = t; i < 512; i += 256)
        YhS[i >> 5][i & 31] = Yh[(size_t)(b * 16 + (i >> 5)) * 32 + (i & 31)];
    for (int i = t; i < 480; i += 256)
        ZoS[i >> 5][i & 31] = Zo[(size_t)(b * 15 + (i >> 5)) * 32 + (i & 31)];
    __syncthreads();
    for (int i = t; i < 512; i += 256) {
        int p = i >> 5, j = i & 31;
        float s = 0.f;
#pragma unroll
        for (int o = 0; o < 15; o++) s += adjS[p][o + 1] * ZoS[o][j];
        PA[p][j] = s;
        float s2 = 0.f;
#pragma unroll
        for (int pp = 0; pp < 16; pp++) s2 += adjS[pp][p] * YhS[pp][j];
        OA[p][j] = s2;
    }
    __syncthreads();
    int p = t >> 4, l = t & 15;
    const float* hp = Hp + (size_t)(b * 16 + p) * 32;
    const float* ho = HoF + (size_t)(b * 16 + l) * 32;
    size_t c = (size_t)b * 256 + t;
    for (int j = 0; j < 29; j++) {
        float v = hp[j] + ho[j] + bg[j] + PA[p][j];
        if (l >= 1) v += OA[l][j];
        outG[c * 29 + j] = v;
    }
}

extern "C" void kernel_launch(void* const* d_in, const int* in_sizes, int n_in,
                              void* d_out, int out_size, void* d_ws, size_t ws_size,
                              hipStream_t stream)
{
    const float* people  = (const float*)d_in[0];
    const float* objects = (const float*)d_in[1];
    const float* context = (const float*)d_in[2];
    const float* spatial = (const float*)d_in[3];
    const float* Wvis_w  = (const float*)d_in[4];
    const float* Wvis_b  = (const float*)d_in[5];
    const float* Wspat_w = (const float*)d_in[6];
    const float* Wspat_b = (const float*)d_in[7];
    const float* Wip_w   = (const float*)d_in[8];
    const float* Wip_b   = (const float*)d_in[9];
    const float* Wref_w  = (const float*)d_in[10];
    const float* Wref_b  = (const float*)d_in[11];
    const float* Watt_w  = (const float*)d_in[12];
    const float* Watt_b  = (const float*)d_in[13];
    const float* Woh_w   = (const float*)d_in[14];
    const float* Woh_b   = (const float*)d_in[15];
    const float* Who_w   = (const float*)d_in[16];
    const float* Who_b   = (const float*)d_in[17];
    const float* Wg_w    = (const float*)d_in[18];
    const float* Wg_b    = (const float*)d_in[19];

    char* ws = (char*)d_ws;
    u16* WspatT = (u16*)(ws + OFF_WSPATT);
    u16* WrefT  = (u16*)(ws + OFF_WREFT);
    u16* WattT  = (u16*)(ws + OFF_WATTT);
    u16* WgT    = (u16*)(ws + OFF_WGT);
    u16* Ppb    = (u16*)(ws + OFF_PP);
    u16* Pob    = (u16*)(ws + OFF_PO);
    u16* Pcb    = (u16*)(ws + OFF_PC);
    float* adjw = (float*)(ws + OFF_ADJ);
    float* Hp   = (float*)(ws + OFF_HP);
    float* HoF  = (float*)(ws + OFF_HOF);
    float* Yh   = (float*)(ws + OFF_YH);
    float* Zo   = (float*)(ws + OFF_ZO);
    u16* WvisT2 = (u16*)(ws + OFF_WVIST2);
    u16* WhoT2  = (u16*)(ws + OFF_WHOT2);
    u16* WohT2  = (u16*)(ws + OFF_WOHT2);
    u16* peoB   = (u16*)(ws + OFF_PEOB);
    u16* objB   = (u16*)(ws + OFF_OBJB);
    u16* ctxB   = (u16*)(ws + OFF_CTXB);
    u16* spatB  = (u16*)(ws + OFF_SPATB);
    float* zeroWS = (float*)(ws + ZERO_OFF);

    float* outI   = (float*)d_out;        // i_ho   [16384]
    float* outRef = outI + 16384;         // p_ref  [16384,29]
    float* outAtt = outI + 491520;        // p_att  [16384,29]
    float* outG   = outI + 966656;        // p_graph[16384,29]

    prep_all<<<1408, 256, 0, stream>>>(people, objects, context, spatial,
        Wvis_w, Who_w, Woh_w, Wspat_w, Wref_w, Watt_w, Wg_w,
        peoB, objB, ctxB, spatB, WvisT2, WhoT2, WohT2,
        WspatT, WrefT, WattT, WgT, zeroWS);

    fused_gemms<<<888, 256, 0, stream>>>(peoB, objB, ctxB, WvisT2,
        WhoT2, Who_b, WohT2, Woh_b, WgT,
        Ppb, Pob, Pcb, Yh, Zo, Hp, HoF);

    mega<<<512, 256, 0, stream>>>(spatB, WspatT, Wspat_b,
                                  Ppb, Pob, Pcb, Wvis_b,
                                  WrefT, Wref_b, WattT, Watt_b,
                                  Wip_w, Wip_b,
                                  outI, outRef, outAtt, adjw);

    pgraph2<<<64, 256, 0, stream>>>(adjw, Hp, HoF, Yh, Zo, Wg_b, outG);
}

// Round 3
// 155.598 us; speedup vs baseline: 1.2829x; 1.0025x over previous
//
#include <hip/hip_runtime.h>

// VSGNet fused pipeline — fp32 in/out, bf16 MFMA compute.
// B=64 P=16 L=16 D=1024 SP=32 PROJ=512 ACT=29, C=16384.
// R11 post-mortem: LDS-dbuf fused dropped below the 45us fill floor (total
// 199.6->156.0). Top-5 now = harness fillBufferAligned (256MiB ws re-poison,
// ~2x45us INSIDE dur_us across all rounds' arithmetic) -> controllable budget
// ~66us: fused ~20, prep ~18, mega ~18, pgraph ~5, gaps ~10.
// R12: (1) prep transpose tiles vectorized: float4 global loads + uint2 bf16
// stores (global insts 32->8/thread); LDS scalar w/ [64][65] pad (2-way=free).
// (2) mega steps 2/4: 16-deep serial MFMA chain split into 4 independent
// accumulator chains (latency ~400cy -> ~100cy exposed per step).
// fused/pgraph untouched (proven).

typedef unsigned short u16;   // bf16 bits
typedef short s16x8 __attribute__((ext_vector_type(8)));
typedef float f32x4 __attribute__((ext_vector_type(4)));

__device__ __forceinline__ u16 f2b(float f) {
    union { float f; unsigned int i; } v; v.f = f;
    unsigned int r = (v.i + 0x7fffu + ((v.i >> 16) & 1u)) >> 16;  // RNE
    return (u16)r;
}
__device__ __forceinline__ float b2f(u16 u) {
    union { float f; unsigned int i; } v; v.i = ((unsigned int)u) << 16; return v.f;
}
__device__ __forceinline__ unsigned int pack2(float x, float y) {
    return (unsigned int)f2b(x) | ((unsigned int)f2b(y) << 16);
}

// ---------------- workspace layout (bytes) ----------------
#define OFF_WSPATT 0u         // [512][32]  bf16
#define OFF_WREFT  32768u     // [32][512]  bf16 (rows 29..31 zero)
#define OFF_WATTT  65536u     // [32][512]  bf16
#define OFF_WGT    98304u     // [32][2048] bf16
#define OFF_PP     229376u    // [1024][512] bf16
#define OFF_PO     1277952u   // [1024][512] bf16
#define OFF_PC     2326528u   // [64][512]  bf16
#define OFF_ADJ    2392064u   // [16384] f32
#define OFF_HP     2457600u   // [1024][32] f32
#define OFF_HOF    2588672u   // [1024][32] f32
#define OFF_YH     2719744u   // [1024][32] f32
#define OFF_ZO     2850816u   // [960][32]  f32
#define ZERO_OFF   2457600u
#define ZERO_LEN   516096u
#define OFF_WVIST2 2973696u   // [512][3072] bf16 (n-major, k contiguous)
#define OFF_WHOT2  6119424u   // [1024][1024] bf16
#define OFF_WOHT2  8216576u   // [1024][1024] bf16
#define OFF_PEOB   10313728u  // [1024][1024] bf16
#define OFF_OBJB   12410880u  // [1024][1024] bf16
#define OFF_CTXB   14508032u  // [64][1024]  bf16
#define OFF_SPATB  14639104u  // [16384][32] bf16

// ---------------- prep: LDS-tiled big transposes + vectorized converts ------
// bids [0,896): 64x64 transpose tiles (Who:256, Woh:256, Wvis:384)
// bids [896,1408): grid-stride converts + small head transposes + ws zeroing
__global__ __launch_bounds__(256) void prep_all(
    const float* __restrict__ people, const float* __restrict__ objects,
    const float* __restrict__ context, const float* __restrict__ spatial,
    const float* __restrict__ Wvis, const float* __restrict__ Who,
    const float* __restrict__ Woh, const float* __restrict__ Wspat,
    const float* __restrict__ Wref, const float* __restrict__ Watt,
    const float* __restrict__ Wg,
    u16* __restrict__ peoB, u16* __restrict__ objB, u16* __restrict__ ctxB,
    u16* __restrict__ spatB, u16* __restrict__ WvisT, u16* __restrict__ WhoT,
    u16* __restrict__ WohT, u16* __restrict__ WspatT, u16* __restrict__ WrefT,
    u16* __restrict__ WattT, u16* __restrict__ WgT, float* __restrict__ zeroWS)
{
    // S[k][n], [64][65] pad: both scalar access phases are 2-way (= free, m136)
    __shared__ float S[64][65];
    int bid = blockIdx.x, t = threadIdx.x;
    if (bid < 896) {
        const float* src; u16* dst; int N, K, kt, nt;
        int tb = bid;
        if (tb < 256)      { src = Who;  dst = WhoT;  K = 1024; N = 1024; kt = tb >> 4; nt = tb & 15; }
        else if (tb < 512) { tb -= 256; src = Woh;  dst = WohT;  K = 1024; N = 1024; kt = tb >> 4; nt = tb & 15; }
        else               { tb -= 512; src = Wvis; dst = WvisT; K = 3072; N = 512;  kt = tb >> 3; nt = tb & 7; }
        int k0 = kt * 64, n0 = nt * 64;
        int r = t >> 4, c4 = (t & 15) * 4;   // 16 rows/pass, 4 cols/thread
#pragma unroll
        for (int i = 0; i < 4; i++) {
            float4 v = *(const float4*)&src[(size_t)(k0 + r + 16 * i) * N + n0 + c4];
            S[r + 16 * i][c4 + 0] = v.x;
            S[r + 16 * i][c4 + 1] = v.y;
            S[r + 16 * i][c4 + 2] = v.z;
            S[r + 16 * i][c4 + 3] = v.w;
        }
        __syncthreads();
#pragma unroll
        for (int i = 0; i < 4; i++) {
            int nn = r + 16 * i;
            unsigned int lo = pack2(S[c4 + 0][nn], S[c4 + 1][nn]);
            unsigned int hi = pack2(S[c4 + 2][nn], S[c4 + 3][nn]);
            *(uint2*)&dst[(size_t)(n0 + nn) * K + k0 + c4] = make_uint2(lo, hi);
        }
        return;
    }
    int g = (bid - 896) * 256 + t;
    const int gsz = 512 * 256;
    for (int i = g; i < 262144; i += gsz) {   // people (1M floats as float4)
        float4 v = ((const float4*)people)[i];
        ((uint2*)peoB)[i] = make_uint2(pack2(v.x, v.y), pack2(v.z, v.w));
    }
    for (int i = g; i < 262144; i += gsz) {   // objects
        float4 v = ((const float4*)objects)[i];
        ((uint2*)objB)[i] = make_uint2(pack2(v.x, v.y), pack2(v.z, v.w));
    }
    for (int i = g; i < 16384; i += gsz) {    // context
        float4 v = ((const float4*)context)[i];
        ((uint2*)ctxB)[i] = make_uint2(pack2(v.x, v.y), pack2(v.z, v.w));
    }
    for (int i = g; i < 131072; i += gsz) {   // spatial
        float4 v = ((const float4*)spatial)[i];
        ((uint2*)spatB)[i] = make_uint2(pack2(v.x, v.y), pack2(v.z, v.w));
    }
    for (int i = g; i < 32256; i += gsz) {    // zero Hp/HoF/Yh/Zo (was memset)
        f32x4 z = {0.f, 0.f, 0.f, 0.f};
        ((f32x4*)zeroWS)[i] = z;
    }
    for (int i = g; i < 512 * 32; i += gsz) {
        int n = i >> 5, k = i & 31;
        WspatT[i] = f2b(Wspat[k * 512 + n]);
    }
    for (int i = g; i < 32 * 512; i += gsz) {
        int n = i >> 9, k = i & 511;
        WrefT[i] = (n < 29) ? f2b(Wref[k * 29 + n]) : (u16)0;
        WattT[i] = (n < 29) ? f2b(Watt[k * 29 + n]) : (u16)0;
    }
    for (int i = g; i < 32 * 2048; i += gsz) {
        int n = i >> 11, k = i & 2047;
        WgT[i] = (n < 29) ? f2b(Wg[k * 29 + n]) : (u16)0;
    }
}

// ---------------- fused post-prep GEMMs (flat 888-block grid) ---------------
// Per-section bijective XCD swizzle (sections start at multiples of 8 in b0,
// so b0%8 == local%8 == XCD): locality within a section, balance across them.
// [0,264):   Pp/Po/Pc = {peoB,objB,ctxB} @ WvisT  (LDS dbuf 64x64)
// [264,760): Yh/Zo relu-projection (LDS dbuf 64x64 + stage2 atomics)
// [760,888): Hp/HoF split-K (atomicAdd, fully preloaded)
__global__ __launch_bounds__(256) void fused_gemms(
    const u16* __restrict__ peoB, const u16* __restrict__ objB,
    const u16* __restrict__ ctxB, const u16* __restrict__ WvisT,
    const u16* __restrict__ WhoT, const float* __restrict__ Who_b,
    const u16* __restrict__ WohT, const float* __restrict__ Woh_b,
    const u16* __restrict__ WgT,
    u16* __restrict__ Pp, u16* __restrict__ Po, u16* __restrict__ Pc,
    float* __restrict__ Yh, float* __restrict__ Zo,
    float* __restrict__ Hp, float* __restrict__ HoF)
{
    // double-buffered K-tiles; [64][72] padding: row stride 144B = 36 banks
    // -> ds_read_b128/ds_write_b128 land balanced 8 words/bank (minimum).
    __shared__ __align__(16) u16 As[2][64][72];
    __shared__ __align__(16) u16 Bs[2][64][72];

    int b0 = blockIdx.x, bid;
    if (b0 < 264)      bid = (b0 & 7) * 33 + (b0 >> 3);
    else if (b0 < 760) { int l = b0 - 264; bid = 264 + (l & 7) * 62 + (l >> 3); }
    else               { int l = b0 - 760; bid = 760 + (l & 7) * 16 + (l >> 3); }
    int t = threadIdx.x;
    int lane = t & 63, w = t >> 6;
    int l16 = lane & 15, q = lane >> 4;
    int wy = w >> 1, wx = w & 1;

    if (bid < 760) {
        // ---------- unified LDS-staged 64x64 tile, K=1024, BK=64 ----------
        const u16 *Ap, *Bp;
        int Bstride, bm, bn, koff = 0, zrm = 0;
        u16* outB = nullptr;
        const float* bb = nullptr; const u16* Wg2 = nullptr; float* U = nullptr;
        if (bid < 264) {
            int bx = bid & 7, ty = bid >> 3;
            if (ty < 16)      { Ap = peoB; outB = Pp; koff = 0;    bm = ty * 64; }
            else if (ty < 32) { Ap = objB; outB = Po; koff = 1024; bm = (ty - 16) * 64; }
            else              { Ap = ctxB; outB = Pc; koff = 2048; bm = 0; }
            bn = bx * 64;
            Bp = WvisT; Bstride = 3072;
        } else {
            int r3 = bid - 264;
            int zz, rt, nbt;
            if (r3 < 256) { zz = 0; rt = r3 >> 4; nbt = r3 & 15; }
            else          { zz = 1; r3 -= 256; rt = r3 >> 4; nbt = r3 & 15; }
            zrm = zz;
            Ap = zz ? objB : peoB;
            Bp = zz ? WohT : WhoT; Bstride = 1024;
            bb = zz ? Woh_b : Who_b;
            Wg2 = zz ? WgT : WgT + 1024;
            U = zz ? Zo : Yh;
            bm = rt * 64; bn = nbt * 64;
        }

        // staging coords: thread t owns rows {tr, 32+tr}, 8 k-cols at tc
        int tr = t >> 3, tc = (t & 7) * 8;
        int a0r = bm + tr, a1r = bm + 32 + tr;
        if (zrm) { a0r = (a0r / 15) * 16 + (a0r % 15) + 1;   // skip no-object slot
                   a1r = (a1r / 15) * 16 + (a1r % 15) + 1; }
        const u16* gA0 = Ap + (size_t)a0r * 1024 + tc;
        const u16* gA1 = Ap + (size_t)a1r * 1024 + tc;
        const u16* gB0 = Bp + (size_t)(bn + tr) * Bstride + koff + tc;
        const u16* gB1 = Bp + (size_t)(bn + 32 + tr) * Bstride + koff + tc;

        // prologue: tile0 -> buf0; tile1 -> regs
        s16x8 rA0 = *(const s16x8*)gA0, rA1 = *(const s16x8*)gA1;
        s16x8 rB0 = *(const s16x8*)gB0, rB1 = *(const s16x8*)gB1;
        gA0 += 64; gA1 += 64; gB0 += 64; gB1 += 64;
        *(s16x8*)&As[0][tr][tc]      = rA0;
        *(s16x8*)&As[0][32 + tr][tc] = rA1;
        *(s16x8*)&Bs[0][tr][tc]      = rB0;
        *(s16x8*)&Bs[0][32 + tr][tc] = rB1;
        rA0 = *(const s16x8*)gA0; rA1 = *(const s16x8*)gA1;
        rB0 = *(const s16x8*)gB0; rB1 = *(const s16x8*)gB1;
        gA0 += 64; gA1 += 64; gB0 += 64; gB1 += 64;
        __syncthreads();

        f32x4 acc00 = {0,0,0,0}, acc01 = {0,0,0,0}, acc10 = {0,0,0,0}, acc11 = {0,0,0,0};
        int cur = 0;
        for (int kt = 0; kt < 16; kt++) {
#pragma unroll
            for (int kk = 0; kk < 2; kk++) {
                s16x8 a0 = *(const s16x8*)&As[cur][wy * 32 + l16][kk * 32 + q * 8];
                s16x8 a1 = *(const s16x8*)&As[cur][wy * 32 + 16 + l16][kk * 32 + q * 8];
                s16x8 b0 = *(const s16x8*)&Bs[cur][wx * 32 + l16][kk * 32 + q * 8];
                s16x8 b1 = *(const s16x8*)&Bs[cur][wx * 32 + 16 + l16][kk * 32 + q * 8];
                acc00 = __builtin_amdgcn_mfma_f32_16x16x32_bf16(a0, b0, acc00, 0, 0, 0);
                acc01 = __builtin_amdgcn_mfma_f32_16x16x32_bf16(a0, b1, acc01, 0, 0, 0);
                acc10 = __builtin_amdgcn_mfma_f32_16x16x32_bf16(a1, b0, acc10, 0, 0, 0);
                acc11 = __builtin_amdgcn_mfma_f32_16x16x32_bf16(a1, b1, acc11, 0, 0, 0);
            }
            if (kt < 15) {
                __syncthreads();                      // everyone done reading cur
                *(s16x8*)&As[cur ^ 1][tr][tc]      = rA0;
                *(s16x8*)&As[cur ^ 1][32 + tr][tc] = rA1;
                *(s16x8*)&Bs[cur ^ 1][tr][tc]      = rB0;
                *(s16x8*)&Bs[cur ^ 1][32 + tr][tc] = rB1;
                if (kt < 14) {                        // prefetch tile kt+2
                    rA0 = *(const s16x8*)gA0; rA1 = *(const s16x8*)gA1;
                    rB0 = *(const s16x8*)gB0; rB1 = *(const s16x8*)gB1;
                    gA0 += 64; gA1 += 64; gB0 += 64; gB1 += 64;
                }
                __syncthreads();                      // next buf ready
                cur ^= 1;
            }
        }

        f32x4 accs[2][2] = {{acc00, acc01}, {acc10, acc11}};
        if (bid < 264) {
            // gemm3 epilogue: bf16 store
#pragma unroll
            for (int ii = 0; ii < 2; ii++)
#pragma unroll
                for (int jj = 0; jj < 2; jj++) {
                    int col = bn + wx * 32 + jj * 16 + l16;
#pragma unroll
                    for (int r = 0; r < 4; r++) {
                        int row = bm + wy * 32 + ii * 16 + q * 4 + r;
                        outB[(size_t)row * 512 + col] = f2b(accs[ii][jj][r]);
                    }
                }
        } else {
            // relu epilogue: bias+relu -> T (reuse As[0]; last compute read buf1)
            u16 (*T)[72] = As[0];
#pragma unroll
            for (int ii = 0; ii < 2; ii++)
#pragma unroll
                for (int jj = 0; jj < 2; jj++) {
                    int col = wx * 32 + jj * 16 + l16;
                    float bv = bb[bn + col];
#pragma unroll
                    for (int rr = 0; rr < 4; rr++) {
                        float v = accs[ii][jj][rr] + bv;
                        T[wy * 32 + ii * 16 + q * 4 + rr][col] = f2b(fmaxf(v, 0.f));
                    }
                }
            __syncthreads();

            // stage 2: U_part[64x32] = T(64x64) @ Wg2[bn:bn+64, :32]
            f32x4 s20 = {0,0,0,0}, s21 = {0,0,0,0};
#pragma unroll
            for (int kk = 0; kk < 64; kk += 32) {
                s16x8 a2 = *(const s16x8*)(&T[w * 16 + l16][kk + q * 8]);
                s16x8 b20 = *(const s16x8*)(Wg2 + (size_t)l16 * 2048 + bn + kk + q * 8);
                s16x8 b21 = *(const s16x8*)(Wg2 + (size_t)(16 + l16) * 2048 + bn + kk + q * 8);
                s20 = __builtin_amdgcn_mfma_f32_16x16x32_bf16(a2, b20, s20, 0, 0, 0);
                s21 = __builtin_amdgcn_mfma_f32_16x16x32_bf16(a2, b21, s21, 0, 0, 0);
            }
#pragma unroll
            for (int rr = 0; rr < 4; rr++) {
                int row = bm + w * 16 + q * 4 + rr;
                atomicAdd(&U[(size_t)row * 32 + l16], s20[rr]);
                atomicAdd(&U[(size_t)row * 32 + 16 + l16], s21[rr]);
            }
        }
    } else {
        // ---------------- bt32 split-K: 128 rows, 128-k chunk ----------------
        // Only 4 k-steps: fully preload all 16 loads, then 16 MFMAs.
        int r3 = bid - 760;
        int bx = r3 & 7, by = (r3 >> 3) & 7, z = r3 >> 6;
        const u16* A  = z ? objB : peoB;
        const u16* BT = z ? WgT + 1024 : WgT;
        float* outF   = z ? HoF : Hp;
        int bm = bx * 128 + w * 32;
        int kb = by * 128;
        const u16* ap0 = A + (size_t)(bm + l16) * 1024 + kb + q * 8;
        const u16* ap1 = A + (size_t)(bm + 16 + l16) * 1024 + kb + q * 8;
        const u16* bp0 = BT + (size_t)l16 * 2048 + kb + q * 8;
        const u16* bp1 = BT + (size_t)(16 + l16) * 2048 + kb + q * 8;
        f32x4 acc00 = {0,0,0,0}, acc01 = {0,0,0,0}, acc10 = {0,0,0,0}, acc11 = {0,0,0,0};
        s16x8 bA0[4], bA1[4], bB0[4], bB1[4];
#pragma unroll
        for (int s = 0; s < 4; s++) {
            bA0[s] = *(const s16x8*)(ap0 + s * 32);
            bA1[s] = *(const s16x8*)(ap1 + s * 32);
            bB0[s] = *(const s16x8*)(bp0 + s * 32);
            bB1[s] = *(const s16x8*)(bp1 + s * 32);
        }
#pragma unroll
        for (int s = 0; s < 4; s++) {
            acc00 = __builtin_amdgcn_mfma_f32_16x16x32_bf16(bA0[s], bB0[s], acc00, 0, 0, 0);
            acc01 = __builtin_amdgcn_mfma_f32_16x16x32_bf16(bA0[s], bB1[s], acc01, 0, 0, 0);
            acc10 = __builtin_amdgcn_mfma_f32_16x16x32_bf16(bA1[s], bB0[s], acc10, 0, 0, 0);
            acc11 = __builtin_amdgcn_mfma_f32_16x16x32_bf16(bA1[s], bB1[s], acc11, 0, 0, 0);
        }
        f32x4 accs[2][2] = {{acc00, acc01}, {acc10, acc11}};
#pragma unroll
        for (int ii = 0; ii < 2; ii++)
#pragma unroll
            for (int jj = 0; jj < 2; jj++)
#pragma unroll
                for (int r = 0; r < 4; r++)
                    atomicAdd(&outF[(size_t)(bm + ii * 16 + q * 4 + r) * 32 + jj * 16 + l16],
                              accs[ii][jj][r]);
    }
}

// ---- mega: per 32-row tile: aho(MFMA) -> p_att -> fref(in-place LDS)+i_ho -> p_ref
__global__ __launch_bounds__(256) void mega(
    const u16* __restrict__ spatB, const u16* __restrict__ WspatT,
    const float* __restrict__ bspat,
    const u16* __restrict__ Pp, const u16* __restrict__ Po,
    const u16* __restrict__ Pc, const float* __restrict__ bvis,
    const u16* __restrict__ WrefT, const float* __restrict__ bref,
    const u16* __restrict__ WattT, const float* __restrict__ batt,
    const float* __restrict__ wip, const float* __restrict__ bip,
    float* __restrict__ outI, float* __restrict__ outRef,
    float* __restrict__ outAtt, float* __restrict__ adjw)
{
    __shared__ u16 tile[32][512];
    __shared__ float part[32][8];
    __shared__ float wipS[512];
    int t = threadIdx.x;
    int b0 = blockIdx.x;
    int bid = (b0 & 7) * 64 + (b0 >> 3);    // bijective XCD swizzle, 512=8*64
    int c0 = bid * 32;
    int lane = t & 63, w = t >> 6;
    int l16 = lane & 15, q = lane >> 4;

    {
        float2 u = *(const float2*)(wip + t * 2);
        wipS[t * 2]     = u.x;
        wipS[t * 2 + 1] = u.y;
    }

    // step 1: aho rows c0..c0+31; wave w owns cols [w*128, w*128+128)
    {
        s16x8 a0 = *(const s16x8*)(spatB + (size_t)(c0 + l16) * 32 + q * 8);
        s16x8 a1 = *(const s16x8*)(spatB + (size_t)(c0 + 16 + l16) * 32 + q * 8);
        const u16* wb = WspatT + (size_t)(w * 128 + l16) * 32 + q * 8;
        s16x8 cb = *(const s16x8*)wb;
        s16x8 nb_ = *(const s16x8*)(wb + 16 * 32);
        wb += 32 * 32;
#pragma unroll
        for (int nt = 0; nt < 8; nt++) {
            s16x8 tb;
            if (nt < 6) { tb = *(const s16x8*)wb; wb += 16 * 32; }
            int n = w * 128 + nt * 16;
            f32x4 acc0 = {0,0,0,0}, acc1 = {0,0,0,0};
            acc0 = __builtin_amdgcn_mfma_f32_16x16x32_bf16(a0, cb, acc0, 0, 0, 0);
            acc1 = __builtin_amdgcn_mfma_f32_16x16x32_bf16(a1, cb, acc1, 0, 0, 0);
            cb = nb_; nb_ = tb;
            float bias = bspat[n + l16];
#pragma unroll
            for (int r = 0; r < 4; r++) {
                tile[q * 4 + r][n + l16]      = f2b(fmaxf(acc0[r] + bias, 0.f));
                tile[16 + q * 4 + r][n + l16] = f2b(fmaxf(acc1[r] + bias, 0.f));
            }
        }
    }
    __syncthreads();

    // step 2: p_att = aho @ WattT^T + batt  (4 independent MFMA chains)
    {
        int rt = w >> 1, ct = w & 1;
        const u16* bp = WattT + (size_t)(ct * 16 + l16) * 512 + q * 8;
        const u16* ar = &tile[rt * 16 + l16][q * 8];
        f32x4 acc0 = {0,0,0,0}, acc1 = {0,0,0,0}, acc2 = {0,0,0,0}, acc3 = {0,0,0,0};
#pragma unroll
        for (int s = 0; s < 16; s += 4) {
            s16x8 a0 = *(const s16x8*)(ar + (s + 0) * 32);
            s16x8 a1 = *(const s16x8*)(ar + (s + 1) * 32);
            s16x8 a2 = *(const s16x8*)(ar + (s + 2) * 32);
            s16x8 a3 = *(const s16x8*)(ar + (s + 3) * 32);
            s16x8 b0 = *(const s16x8*)(bp + (s + 0) * 32);
            s16x8 b1 = *(const s16x8*)(bp + (s + 1) * 32);
            s16x8 b2 = *(const s16x8*)(bp + (s + 2) * 32);
            s16x8 b3 = *(const s16x8*)(bp + (s + 3) * 32);
            acc0 = __builtin_amdgcn_mfma_f32_16x16x32_bf16(a0, b0, acc0, 0, 0, 0);
            acc1 = __builtin_amdgcn_mfma_f32_16x16x32_bf16(a1, b1, acc1, 0, 0, 0);
            acc2 = __builtin_amdgcn_mfma_f32_16x16x32_bf16(a2, b2, acc2, 0, 0, 0);
            acc3 = __builtin_amdgcn_mfma_f32_16x16x32_bf16(a3, b3, acc3, 0, 0, 0);
        }
        f32x4 acc = (acc0 + acc1) + (acc2 + acc3);
        int col = ct * 16 + l16;
        if (col < 29) {
            float bias = batt[col];
#pragma unroll
            for (int r = 0; r < 4; r++) {
                int row = c0 + rt * 16 + q * 4 + r;
                outAtt[(size_t)row * 29 + col] = acc[r] + bias;
            }
        }
    }
    __syncthreads();

    // step 3: fref = relu(Pp+Po+Pc+bvis) * aho (in-place); i_ho partials
    {
        int row = t >> 3, g = t & 7;
        int c = c0 + row;
        int rp = c >> 4, bimg = c >> 8;
        int ro = bimg * 16 + (c & 15);
        const u16* ppr = Pp + (size_t)rp * 512;
        const u16* por = Po + (size_t)ro * 512;
        const u16* pcr = Pc + (size_t)bimg * 512;
        float ps = 0.f;
#pragma unroll 4
        for (int j = 0; j < 64; j += 2) {
            int col = g * 64 + j;
            unsigned int upp = *(const unsigned int*)(ppr + col);
            unsigned int upo = *(const unsigned int*)(por + col);
            unsigned int upc = *(const unsigned int*)(pcr + col);
            float2 bv = *(const float2*)(bvis + col);
            unsigned int uah = *(const unsigned int*)(&tile[row][col]);
            float fv0 = fmaxf(b2f((u16)(upp & 0xffff)) + b2f((u16)(upo & 0xffff))
                            + b2f((u16)(upc & 0xffff)) + bv.x, 0.f);
            float fv1 = fmaxf(b2f((u16)(upp >> 16)) + b2f((u16)(upo >> 16))
                            + b2f((u16)(upc >> 16)) + bv.y, 0.f);
            float fr0 = fv0 * b2f((u16)(uah & 0xffff));
            float fr1 = fv1 * b2f((u16)(uah >> 16));
            *(unsigned int*)(&tile[row][col]) = pack2(fr0, fr1);
            ps += fr0 * wipS[col] + fr1 * wipS[col + 1];
        }
        part[row][g] = ps;
    }
    __syncthreads();

    if (t < 32) {
        float s = part[t][0] + part[t][1] + part[t][2] + part[t][3]
                + part[t][4] + part[t][5] + part[t][6] + part[t][7] + bip[0];
        outI[c0 + t] = s;
        adjw[c0 + t] = 1.f / (1.f + expf(-s));
    }

    // step 4: p_ref = fref @ WrefT^T + bref  (4 independent MFMA chains)
    {
        int rt = w >> 1, ct = w & 1;
        const u16* bp = WrefT + (size_t)(ct * 16 + l16) * 512 + q * 8;
        const u16* ar = &tile[rt * 16 + l16][q * 8];
        f32x4 acc0 = {0,0,0,0}, acc1 = {0,0,0,0}, acc2 = {0,0,0,0}, acc3 = {0,0,0,0};
#pragma unroll
        for (int s = 0; s < 16; s += 4) {
            s16x8 a0 = *(const s16x8*)(ar + (s + 0) * 32);
            s16x8 a1 = *(const s16x8*)(ar + (s + 1) * 32);
            s16x8 a2 = *(const s16x8*)(ar + (s + 2) * 32);
            s16x8 a3 = *(const s16x8*)(ar + (s + 3) * 32);
            s16x8 b0 = *(const s16x8*)(bp + (s + 0) * 32);
            s16x8 b1 = *(const s16x8*)(bp + (s + 1) * 32);
            s16x8 b2 = *(const s16x8*)(bp + (s + 2) * 32);
            s16x8 b3 = *(const s16x8*)(bp + (s + 3) * 32);
            acc0 = __builtin_amdgcn_mfma_f32_16x16x32_bf16(a0, b0, acc0, 0, 0, 0);
            acc1 = __builtin_amdgcn_mfma_f32_16x16x32_bf16(a1, b1, acc1, 0, 0, 0);
            acc2 = __builtin_amdgcn_mfma_f32_16x16x32_bf16(a2, b2, acc2, 0, 0, 0);
            acc3 = __builtin_amdgcn_mfma_f32_16x16x32_bf16(a3, b3, acc3, 0, 0, 0);
        }
        f32x4 acc = (acc0 + acc1) + (acc2 + acc3);
        int col = ct * 16 + l16;
        if (col < 29) {
            float bias = bref[col];
#pragma unroll
            for (int r = 0; r < 4; r++) {
                int row = c0 + rt * 16 + q * 4 + r;
                outRef[(size_t)row * 29 + col] = acc[r] + bias;
            }
        }
    }
}

// ---- p_graph: per image, tiny adj contractions + broadcast sum -------------
__global__ __launch_bounds__(256) void pgraph2(
    const float* __restrict__ adjw, const float* __restrict__ Hp,
    const float* __restrict__ HoF, const float* __restrict__ Yh,
    const float* __restrict__ Zo, const float* __restrict__ bg,
    float* __restrict__ outG)
{
    int b = blockIdx.x, t = threadIdx.x;
    __shared__ float adjS[16][16];
    __shared__ float YhS[16][32];
    __shared__ float ZoS[15][32];
    __shared__ float PA[16][32];
    __shared__ float OA[16][32];
    adjS[t >> 4][t & 15] = adjw[b * 256 + t];
    for (int i = t; i < 512; i += 256)
        YhS[i >> 5][i & 31] = Yh[(size_t)(b * 16 + (i >> 5)) * 32 + (i & 31)];
    for (int i = t; i < 480; i += 256)
        ZoS[i >> 5][i & 31] = Zo[(size_t)(b * 15 + (i >> 5)) * 32 + (i & 31)];
    __syncthreads();
    for (int i = t; i < 512; i += 256) {
        int p = i >> 5, j = i & 31;
        float s = 0.f;
#pragma unroll
        for (int o = 0; o < 15; o++) s += adjS[p][o + 1] * ZoS[o][j];
        PA[p][j] = s;
        float s2 = 0.f;
#pragma unroll
        for (int pp = 0; pp < 16; pp++) s2 += adjS[pp][p] * YhS[pp][j];
        OA[p][j] = s2;
    }
    __syncthreads();
    int p = t >> 4, l = t & 15;
    const float* hp = Hp + (size_t)(b * 16 + p) * 32;
    const float* ho = HoF + (size_t)(b * 16 + l) * 32;
    size_t c = (size_t)b * 256 + t;
    for (int j = 0; j < 29; j++) {
        float v = hp[j] + ho[j] + bg[j] + PA[p][j];
        if (l >= 1) v += OA[l][j];
        outG[c * 29 + j] = v;
    }
}

extern "C" void kernel_launch(void* const* d_in, const int* in_sizes, int n_in,
                              void* d_out, int out_size, void* d_ws, size_t ws_size,
                              hipStream_t stream)
{
    const float* people  = (const float*)d_in[0];
    const float* objects = (const float*)d_in[1];
    const float* context = (const float*)d_in[2];
    const float* spatial = (const float*)d_in[3];
    const float* Wvis_w  = (const float*)d_in[4];
    const float* Wvis_b  = (const float*)d_in[5];
    const float* Wspat_w = (const float*)d_in[6];
    const float* Wspat_b = (const float*)d_in[7];
    const float* Wip_w   = (const float*)d_in[8];
    const float* Wip_b   = (const float*)d_in[9];
    const float* Wref_w  = (const float*)d_in[10];
    const float* Wref_b  = (const float*)d_in[11];
    const float* Watt_w  = (const float*)d_in[12];
    const float* Watt_b  = (const float*)d_in[13];
    const float* Woh_w   = (const float*)d_in[14];
    const float* Woh_b   = (const float*)d_in[15];
    const float* Who_w   = (const float*)d_in[16];
    const float* Who_b   = (const float*)d_in[17];
    const float* Wg_w    = (const float*)d_in[18];
    const float* Wg_b    = (const float*)d_in[19];

    char* ws = (char*)d_ws;
    u16* WspatT = (u16*)(ws + OFF_WSPATT);
    u16* WrefT  = (u16*)(ws + OFF_WREFT);
    u16* WattT  = (u16*)(ws + OFF_WATTT);
    u16* WgT    = (u16*)(ws + OFF_WGT);
    u16* Ppb    = (u16*)(ws + OFF_PP);
    u16* Pob    = (u16*)(ws + OFF_PO);
    u16* Pcb    = (u16*)(ws + OFF_PC);
    float* adjw = (float*)(ws + OFF_ADJ);
    float* Hp   = (float*)(ws + OFF_HP);
    float* HoF  = (float*)(ws + OFF_HOF);
    float* Yh   = (float*)(ws + OFF_YH);
    float* Zo   = (float*)(ws + OFF_ZO);
    u16* WvisT2 = (u16*)(ws + OFF_WVIST2);
    u16* WhoT2  = (u16*)(ws + OFF_WHOT2);
    u16* WohT2  = (u16*)(ws + OFF_WOHT2);
    u16* peoB   = (u16*)(ws + OFF_PEOB);
    u16* objB   = (u16*)(ws + OFF_OBJB);
    u16* ctxB   = (u16*)(ws + OFF_CTXB);
    u16* spatB  = (u16*)(ws + OFF_SPATB);
    float* zeroWS = (float*)(ws + ZERO_OFF);

    float* outI   = (float*)d_out;        // i_ho   [16384]
    float* outRef = outI + 16384;         // p_ref  [16384,29]
    float* outAtt = outI + 491520;        // p_att  [16384,29]
    float* outG   = outI + 966656;        // p_graph[16384,29]

    prep_all<<<1408, 256, 0, stream>>>(people, objects, context, spatial,
        Wvis_w, Who_w, Woh_w, Wspat_w, Wref_w, Watt_w, Wg_w,
        peoB, objB, ctxB, spatB, WvisT2, WhoT2, WohT2,
        WspatT, WrefT, WattT, WgT, zeroWS);

    fused_gemms<<<888, 256, 0, stream>>>(peoB, objB, ctxB, WvisT2,
        WhoT2, Who_b, WohT2, Woh_b, WgT,
        Ppb, Pob, Pcb, Yh, Zo, Hp, HoF);

    mega<<<512, 256, 0, stream>>>(spatB, WspatT, Wspat_b,
                                  Ppb, Pob, Pcb, Wvis_b,
                                  WrefT, Wref_b, WattT, Watt_b,
                                  Wip_w, Wip_b,
                                  outI, outRef, outAtt, adjw);

    pgraph2<<<64, 256, 0, stream>>>(adjw, Hp, HoF, Yh, Zo, Wg_b, outG);
}